// Round 11
// baseline (1075.503 us; speedup 1.0000x reference)
//
#include <hip/hip_runtime.h>
#include <stdint.h>

#define N_NODES 100000
#define N_EDGES 1600000
#define CH 128
#define EDGE_DIM 16
#define KUPD 256
#define NPW 8

typedef __attribute__((ext_vector_type(8))) short short8v;   // 8 bf16 (4 VGPRs)
typedef __attribute__((ext_vector_type(4))) float f32x4;

__device__ __forceinline__ float bf2f(ushort u) {
  union { uint i; float f; } c; c.i = ((uint)u) << 16; return c.f;
}
__device__ __forceinline__ ushort f2bf(float f) {
  union { float f; uint i; } c; c.f = f;
  return (ushort)((c.i + 0x7FFFu + ((c.i >> 16) & 1u)) >> 16);
}
__device__ __forceinline__ float ldf(const void* p, int f32, size_t i) {
  return f32 ? ((const float*)p)[i] : bf2f(((const ushort*)p)[i]);
}
__device__ __forceinline__ float2 ld2(const void* p, int f32, size_t pi) {
  if (f32) return ((const float2*)p)[pi];
  uint u = ((const uint*)p)[pi];
  return make_float2(bf2f((ushort)(u & 0xFFFF)), bf2f((ushort)(u >> 16)));
}
__device__ __forceinline__ float4 ld4(const void* p, int f32, size_t qi) {
  if (f32) return ((const float4*)p)[qi];
  uint2 u = ((const uint2*)p)[qi];
  float4 r;
  r.x = bf2f((ushort)(u.x & 0xFFFF)); r.y = bf2f((ushort)(u.x >> 16));
  r.z = bf2f((ushort)(u.y & 0xFFFF)); r.w = bf2f((ushort)(u.y >> 16));
  return r;
}
// x_sel: 0 = force bf16, 1 = use detected x flag, 2 = force f32
__device__ __forceinline__ int resolve_f32(int x_sel, const int* flags) {
  return (x_sel == 2) ? 1 : (x_sel == 1 ? flags[1] : 0);
}
// MFMA A/B k-mapping candidates. g = lane>>4, j = frag element 0..7.
__device__ __forceinline__ int kmap(int MAP, int g, int j, int step) {
  return MAP ? (step * 32 + 8 * g + j)
             : (step * 32 + 16 * (j >> 2) + 4 * g + (j & 3));
}

// ---------------------------------------------------------------- detection + MFMA probe (merged)
// flags[0]=1 -> edge_index int32 [2,E]. flags[1..3]=1 -> x / edge_attr / weights f32.
// flags[4] = MFMA k-mapping (0/1) or 2 = fallback.
__global__ __launch_bounds__(256) void detect_probe(const int* __restrict__ ei,
                                                    const ushort* __restrict__ xu,
                                                    const ushort* __restrict__ eau,
                                                    const ushort* __restrict__ wu,
                                                    int* __restrict__ flags) {
  __shared__ ushort A[16 * 32];
  __shared__ ushort B[32 * 16];
  int any = 0, fx = 0, fe = 0, fw = 0;
  for (int i = threadIdx.x; i < 4096; i += 256) any |= ei[2 * i + 1];
  for (int i = threadIdx.x; i < 16384; i += 256) {
    fx |= (((xu[2 * i] >> 7) & 0xFF) == 0xFF);
    fe |= (((eau[2 * i] >> 7) & 0xFF) == 0xFF);
  }
  for (int i = threadIdx.x; i < 8192; i += 256) {
    fw |= (((wu[2 * i] >> 7) & 0xFF) == 0xFF);
  }
  if (any) atomicOr(flags + 0, 1);
  if (fx)  atomicOr(flags + 1, 1);
  if (fe)  atomicOr(flags + 2, 1);
  if (fw)  atomicOr(flags + 3, 1);
  for (int idx = threadIdx.x; idx < 512; idx += 256) {
    int i = idx >> 5, k = idx & 31;
    A[idx] = f2bf((float)((i * 5 + k * 3) % 13 - 6));
    int k2 = idx >> 4, c = idx & 15;
    B[idx] = f2bf((float)((k2 * 7 + c * 11) % 15 - 7));
  }
  __syncthreads();
  if (threadIdx.x < 64) {
    const int lane = threadIdx.x;
    const int col = lane & 15, g = lane >> 4;
    float cr[4];
#pragma unroll
    for (int r = 0; r < 4; ++r) {
      int row = g * 4 + r;
      float s = 0.f;
      for (int k = 0; k < 32; ++k) s += bf2f(A[row * 32 + k]) * bf2f(B[k * 16 + col]);
      cr[r] = s;
    }
    int win = 2;
    for (int MAP = 0; MAP < 2; ++MAP) {
      if (win != 2) break;
      short8v a, b;
#pragma unroll
      for (int j = 0; j < 8; ++j) {
        int k = kmap(MAP, g, j, 0);
        a[j] = (short)A[(lane & 15) * 32 + k];
        b[j] = (short)B[k * 16 + col];
      }
      f32x4 z = {0.f, 0.f, 0.f, 0.f};
      f32x4 d = __builtin_amdgcn_mfma_f32_16x16x32_bf16(a, b, z, 0, 0, 0);
      int good = 1;
#pragma unroll
      for (int r = 0; r < 4; ++r) good &= (d[r] == cr[r]);
      if (__all(good)) win = MAP;
    }
    if (lane == 0) flags[4] = win;
  }
}

__device__ __forceinline__ void load_edge(const int* __restrict__ ei, int i32, int e,
                                          int& s, int& d) {
  if (i32) { s = ei[e]; d = ei[N_EDGES + e]; }
  else     { s = ei[2 * e]; d = ei[2 * N_EDGES + 2 * e]; }
  s = min(max(s, 0), N_NODES - 1);
  d = min(max(d, 0), N_NODES - 1);
}

// ---------------------------------------------------------------- degree count (dst only)
__global__ __launch_bounds__(256) void count_kernel(const int* __restrict__ ei,
                                                    const int* __restrict__ flags,
                                                    int* __restrict__ cnt) {
  int e = blockIdx.x * 256 + threadIdx.x;
  if (e >= N_EDGES) return;
  int d = flags[0] ? ei[N_EDGES + e] : ei[2 * N_EDGES + 2 * e];
  d = min(max(d, 0), N_NODES - 1);
  atomicAdd(&cnt[d], 1);
}

// ---------------------------------------------------------------- exclusive prefix scan of cnt -> rowptr
__global__ __launch_bounds__(1024) void scan_kernel(const int* __restrict__ cnt,
                                                    int* __restrict__ rowptr) {
  __shared__ int part[1024];
  const int t = threadIdx.x;
  const int CHUNK = (N_NODES + 1023) / 1024;  // 98
  int base = t * CHUNK;
  int lim = min(base + CHUNK, N_NODES);
  int s = 0;
  for (int i = base; i < lim; ++i) s += cnt[i];
  part[t] = s;
  __syncthreads();
  for (int off = 1; off < 1024; off <<= 1) {
    int v = (t >= off) ? part[t - off] : 0;
    __syncthreads();
    part[t] += v;
    __syncthreads();
  }
  int excl = (t == 0) ? 0 : part[t - 1];
  for (int i = base; i < lim; ++i) { rowptr[i] = excl; excl += cnt[i]; }
  if (t == 1023) rowptr[N_NODES] = part[1023];
}

// ---------------------------------------------------------------- CSR scatter + ea->bf16 conversion
// sev {src,eid} sorted by dst. ALSO emits eabf: edge attrs as bf16 pairs in
// linear dim order (uint i = dims 2i,2i+1) -- agg's MFMA A-frags load these
// directly (no per-edge f2bf/pack VALU in the hot kernel). Same f2bf rounding
// that agg applied before -> consumed values bit-identical.
__global__ __launch_bounds__(256) void scatter_kernel(const int* __restrict__ ei,
                                                      const void* __restrict__ ea,
                                                      const int* __restrict__ flags,
                                                      const int* __restrict__ rowptr,
                                                      int* __restrict__ fill,
                                                      int2* __restrict__ sev,
                                                      uint* __restrict__ eabf) {
  int e = blockIdx.x * 256 + threadIdx.x;
  if (e >= N_EDGES) return;
  int s, d;
  load_edge(ei, flags[0], e, s, d);
  int pos = atomicAdd(&fill[d], 1);
  sev[rowptr[d] + pos] = make_int2(s, e);
  const int ef = flags[2];
#pragma unroll
  for (int qv = 0; qv < 4; ++qv) {
    float4 v = ld4(ea, ef, (size_t)e * 4 + qv);
    eabf[(size_t)e * 8 + 2 * qv]     = (uint)f2bf(v.x) | ((uint)f2bf(v.y) << 16);
    eabf[(size_t)e * 8 + 2 * qv + 1] = (uint)f2bf(v.z) | ((uint)f2bf(v.w) << 16);
  }
}

// ---------------------------------------------------------------- unified W pre-shuffle
// Groups 0..191: upd K=256 (8x8) + msg K=128 (8x4). 192..207: W_e K=32-padded
// frags. Group 208: zero ybf row N_NODES (tail-mask row).
__global__ __launch_bounds__(256) void wshuf_all(const void* __restrict__ wu1,
                                                 const void* __restrict__ wu2,
                                                 const void* __restrict__ wm1,
                                                 const void* __restrict__ wm2,
                                                 const int* __restrict__ flags,
                                                 ushort* __restrict__ ou1,
                                                 ushort* __restrict__ ou2,
                                                 ushort* __restrict__ om1,
                                                 ushort* __restrict__ om2,
                                                 ushort* __restrict__ oz1,
                                                 ushort* __restrict__ oz2,
                                                 uint* __restrict__ ybf) {
  const int MAP = flags[4], wf = flags[3];
  if (MAP == 2) return;
  int tid = blockIdx.x * 256 + threadIdx.x;  // 209 groups * 64 = 13376
  if (tid >= 13376) return;
  int gg = tid >> 6, lane = tid & 63;
  int col16 = lane & 15, g = lane >> 4;
  if (gg == 208) {
    ybf[(size_t)N_NODES * 64 + lane] = 0u;
    return;
  }
  if (gg >= 192) {  // W_e frags
    int l = gg - 192;
    const void* W = (l < 8) ? wm1 : wm2;
    ushort* dst = (l < 8) ? oz1 : oz2;
    int t = l & 7;
#pragma unroll
    for (int j = 0; j < 8; ++j) {
      int k = kmap(MAP, g, j, 0);
      ushort v = (k < 16) ? f2bf(ldf(W, wf, (size_t)(CH + k) * CH + t * 16 + col16)) : (ushort)0;
      dst[(size_t)t * 512 + lane * 8 + j] = v;
    }
    return;
  }
  const void* W; ushort* dst; int t, step, ts;
  if (gg < 64)       { W = wu1; dst = ou1; int l = gg;       t = l >> 3; step = l & 7; ts = t * 8 + step; }
  else if (gg < 128) { W = wu2; dst = ou2; int l = gg - 64;  t = l >> 3; step = l & 7; ts = t * 8 + step; }
  else if (gg < 160) { W = wm1; dst = om1; int l = gg - 128; t = l >> 2; step = l & 3; ts = t * 4 + step; }
  else               { W = wm2; dst = om2; int l = gg - 160; t = l >> 2; step = l & 3; ts = t * 4 + step; }
  int col = t * 16 + col16;
#pragma unroll
  for (int j = 0; j < 8; ++j) {
    int k = kmap(MAP, g, j, step);
    dst[(size_t)ts * 512 + lane * 8 + j] = f2bf(ldf(W, wf, (size_t)k * CH + col));
  }
}

// ---------------------------------------------------------------- node GEMM y = x @ Wm[0:128] + b on MFMA
// xf==0 fast path: input already bf16 (x bf16 or hbf) -> stage uint2 directly.
template <int MAP>
__device__ __forceinline__ void gemm_mfma_body(const void* __restrict__ x, int xf,
                                               const ushort* __restrict__ wshm,
                                               const void* __restrict__ bmsg, int wf,
                                               uint* __restrict__ ybf,
                                               int n0, int lane, char* lds) {
  const int srow = lane >> 2;
  const int q = lane & 3;
  {
    uint sw = (uint)((srow & 7) << 4);
#pragma unroll
    for (int i = 0; i < 8; ++i) {
      int qi = q + 4 * i;
      uint2 pk;
      if (xf) {
        float4 v = ((const float4*)x)[(size_t)(n0 + srow) * 32 + qi];
        pk.x = (uint)f2bf(v.x) | ((uint)f2bf(v.y) << 16);
        pk.y = (uint)f2bf(v.z) | ((uint)f2bf(v.w) << 16);
      } else {
        pk = ((const uint2*)x)[(size_t)(n0 + srow) * 32 + qi];
      }
      *(uint2*)(lds + (((uint)srow * 256u + (uint)qi * 8u) ^ sw)) = pk;
    }
  }
  asm volatile("s_waitcnt lgkmcnt(0) vmcnt(0)" ::: "memory");
  __builtin_amdgcn_sched_barrier(0);

  const int col = lane & 15, g = lane >> 4;
  const int ra = lane & 15;
  const uint asw = (uint)((ra & 7) << 4);
  f32x4 acc[8];
#pragma unroll
  for (int t = 0; t < 8; ++t) acc[t] = (f32x4){0.f, 0.f, 0.f, 0.f};

#pragma unroll
  for (int step = 0; step < 4; ++step) {
    short8v a;
    if (MAP) {
      uint byte = (uint)ra * 256u + (uint)(step * 32 + 8 * g) * 2u;
      *(uint4*)&a = *(const uint4*)(lds + (byte ^ asw));
    } else {
      uint b0 = (uint)ra * 256u + (uint)(step * 32 + 4 * g) * 2u;
      uint b1 = b0 + 32u;
      uint2 lo = *(const uint2*)(lds + (b0 ^ asw));
      uint2 hi = *(const uint2*)(lds + (b1 ^ asw));
      uint4 pk = make_uint4(lo.x, lo.y, hi.x, hi.y);
      *(uint4*)&a = pk;
    }
#pragma unroll
    for (int t = 0; t < 8; ++t) {
      short8v b = *(const short8v*)(wshm + ((size_t)(t * 4 + step) * 512 + lane * 8));
      acc[t] = __builtin_amdgcn_mfma_f32_16x16x32_bf16(a, b, acc[t], 0, 0, 0);
    }
  }

#pragma unroll
  for (int u = 0; u < 4; ++u) {
    float b0v = ldf(bmsg, wf, u * 32 + col);
    float b1v = ldf(bmsg, wf, u * 32 + 16 + col);
#pragma unroll
    for (int r = 0; r < 4; ++r) {
      uint pk = (uint)f2bf(acc[2 * u][r] + b0v) | ((uint)f2bf(acc[2 * u + 1][r] + b1v) << 16);
      ybf[(uint)(n0 + g * 4 + r) * 64u + (uint)(u * 16 + col)] = pk;
    }
  }
}

// f32 fallback: canonical ybf pairing (2*lane, 2*lane+1).
__device__ __forceinline__ void gemm_f32_body(const void* __restrict__ x, int xf,
                                              const void* __restrict__ W, int wf,
                                              const void* __restrict__ b,
                                              uint* __restrict__ ybf,
                                              int wave_n0, int lane, char* ldsc) {
  float* xs = (float*)ldsc;  // [8][128] per-wave 4KB
  for (int c = 0; c < 2; ++c) {
    int n0 = wave_n0 + c * 8;
#pragma unroll
    for (int r = 0; r < NPW; ++r) {
      float2 a = ld2(x, xf, (size_t)(n0 + r) * 64 + lane);
      xs[r * 128 + 2 * lane]     = a.x;
      xs[r * 128 + 2 * lane + 1] = a.y;
    }
    asm volatile("s_waitcnt lgkmcnt(0)" ::: "memory");
    __builtin_amdgcn_sched_barrier(0);
    float acc0[NPW], acc1[NPW];
#pragma unroll
    for (int r = 0; r < NPW; ++r) { acc0[r] = 0.f; acc1[r] = 0.f; }
#pragma unroll 4
    for (int k = 0; k < CH; k += 2) {
      float2 w0 = ld2(W, wf, (size_t)k * 64 + lane);
      float2 w1 = ld2(W, wf, (size_t)(k + 1) * 64 + lane);
#pragma unroll
      for (int r = 0; r < NPW; ++r) {
        float2 a = *(const float2*)&xs[r * 128 + k];
        acc0[r] += a.x * w0.x;
        acc1[r] += a.x * w0.y;
        acc0[r] += a.y * w1.x;
        acc1[r] += a.y * w1.y;
      }
    }
    float2 bb = ld2(b, wf, lane);
#pragma unroll
    for (int r = 0; r < NPW; ++r) {
      uint pk = (uint)f2bf(acc0[r] + bb.x) | ((uint)f2bf(acc1[r] + bb.y) << 16);
      ybf[(uint)(n0 + r) * 64u + (uint)lane] = pk;
    }
  }
}

// xa/sa: input for the MFMA path (layer2: hbf, bf16). xb/sb: fallback input
// (layer2: h f32 in d_out).
__global__ __launch_bounds__(256) void gemm_node(const void* __restrict__ xa, int sa,
                                                 const void* __restrict__ xb, int sb,
                                                 const ushort* __restrict__ wshm,
                                                 const void* __restrict__ W,
                                                 const void* __restrict__ b,
                                                 const int* __restrict__ flags,
                                                 uint* __restrict__ ybf) {
  __shared__ char lds[16384];  // 4 KB per wave
  const int wave = threadIdx.x >> 6;
  const int lane = threadIdx.x & 63;
  const int wid = blockIdx.x * 4 + wave;
  if (wid >= N_NODES / 16) return;
  const int n0 = wid * 16;
  const int wf = flags[3];
  const int MAP = flags[4];
  char* myl = lds + wave * 4096;
  if (MAP == 0)      gemm_mfma_body<0>(xa, resolve_f32(sa, flags), wshm, b, wf, ybf, n0, lane, myl);
  else if (MAP == 1) gemm_mfma_body<1>(xa, resolve_f32(sa, flags), wshm, b, wf, ybf, n0, lane, myl);
  else               gemm_f32_body(xb, resolve_f32(sb, flags), W, wf, b, ybf, n0, lane, myl);
}

// ---------------------------------------------------------------- CSR aggregation with edge-MFMA, 8 nodes/wave
// A-frags load directly from eabf (pre-converted bf16) -- no f2bf/pack VALU.
// Output: bf16 MEAN (inv folded; same f2bf(part*inv) upd computed before) in
// linear channel layout -> upd reads 25.6MB instead of 51MB f32.
template <int MAP>
__device__ __forceinline__ void agg_mfma_body(const uint* __restrict__ ybf,
                                              const uint* __restrict__ eabf,
                                              const ushort* __restrict__ wze,
                                              const int* __restrict__ rowptr,
                                              const int2* __restrict__ sev,
                                              ushort* __restrict__ aggbf,
                                              int n0, int lane) {
  const int col = lane & 15, g = lane >> 4;
  short8v bfr[8];
#pragma unroll
  for (int t = 0; t < 8; ++t)
    bfr[t] = *(const short8v*)(wze + ((size_t)t * 512 + lane * 8));

  for (int ni = 0; ni < 8; ++ni) {
    const int n = n0 + ni;
    const int beg = rowptr[n], end = rowptr[n + 1];
    f32x4 acc[8];
#pragma unroll
    for (int t = 0; t < 8; ++t) acc[t] = (f32x4){0.f, 0.f, 0.f, 0.f};

    for (int j0 = beg; j0 < end; j0 += 16) {
      int jr = j0 + col;              // this lane stages A-row 'col'
      uint amask = (jr < end) ? 0xFFFFFFFFu : 0u;
      if (jr > end - 1) jr = end - 1;
      int2 p = sev[jr];
      int e = p.y;
      short8v a;
      if (MAP == 1) {                 // k = 8g+j: dims 8g..8g+7 (g<2), zero g>=2
        uint4 pk;
        if (g < 2) {
          pk = ((const uint4*)eabf)[(size_t)e * 2 + g];
          pk.x &= amask; pk.y &= amask; pk.z &= amask; pk.w &= amask;
        } else {
          pk = make_uint4(0, 0, 0, 0);
        }
        *(uint4*)&a = pk;
      } else {                        // MAP0: j<4 -> k=4g+j; j>=4 -> zero
        uint2 qv = ((const uint2*)eabf)[(size_t)e * 4 + g];
        uint4 pk;
        pk.x = qv.x & amask;
        pk.y = qv.y & amask;
        pk.z = 0; pk.w = 0;
        *(uint4*)&a = pk;
      }
      f32x4 zz = {0.f, 0.f, 0.f, 0.f};
      f32x4 zf[8];
#pragma unroll
      for (int t = 0; t < 8; ++t)
        zf[t] = __builtin_amdgcn_mfma_f32_16x16x32_bf16(a, bfr[t], zz, 0, 0, 0);

      int myS = p.x;
#pragma unroll
      for (int r = 0; r < 4; ++r) {
        int slot = g * 4 + r;
        int s = __shfl(myS, slot);
        if (j0 + slot >= end) s = N_NODES;  // zero row -> +0.0
        uint yb = (uint)s * 64u + (uint)col;
#pragma unroll
        for (int u = 0; u < 4; ++u) {
          uint yu = ybf[yb + (uint)u * 16u];
          float lo = bf2f((ushort)(yu & 0xFFFF));
          float hi = bf2f((ushort)(yu >> 16));
          acc[2 * u][r]     += fmaxf(lo + zf[2 * u][r], 0.f);
          acc[2 * u + 1][r] += fmaxf(hi + zf[2 * u + 1][r], 0.f);
        }
      }
    }
    int c = end - beg;
    float inv = 1.f / (float)(c > 1 ? c : 1);
    float part[8];
#pragma unroll
    for (int t = 0; t < 8; ++t) {
      part[t] = (acc[t][0] + acc[t][1]) + (acc[t][2] + acc[t][3]);
      part[t] += __shfl_xor(part[t], 16);
      part[t] += __shfl_xor(part[t], 32);
    }
    aggbf[(size_t)n * CH + 32 * g + col]      = f2bf(part[2 * g] * inv);
    aggbf[(size_t)n * CH + 32 * g + 16 + col] = f2bf(part[2 * g + 1] * inv);
  }
}

// Scalar fallback (MAP==2): f32 agg (sum, no inv), canonical pairing, f32 ea.
__device__ __forceinline__ void agg_f32_body(const uint* __restrict__ ybf,
                                             const void* __restrict__ ea, int ef,
                                             const void* __restrict__ W, int wf,
                                             const int* __restrict__ rowptr,
                                             const int2* __restrict__ sev,
                                             float* __restrict__ agg,
                                             int n0, int lane) {
  const int c0 = 2 * lane, c1 = c0 + 1;
  float wex[EDGE_DIM], wey[EDGE_DIM];
#pragma unroll
  for (int k = 0; k < EDGE_DIM; ++k) {
    wex[k] = ldf(W, wf, (size_t)(CH + k) * CH + c0);
    wey[k] = ldf(W, wf, (size_t)(CH + k) * CH + c1);
  }
  for (int ni = 0; ni < 8; ++ni) {
    const int n = n0 + ni;
    const int beg = rowptr[n], end = rowptr[n + 1];
    float acc0 = 0.f, acc1 = 0.f;
    for (int j = beg; j < end; ++j) {
      int2 p = sev[j];
      int s = __builtin_amdgcn_readfirstlane(p.x), e = __builtin_amdgcn_readfirstlane(p.y);
      uint yu = ybf[(size_t)s * 64 + lane];
      float4 q0 = ld4(ea, ef, (size_t)e * 4 + 0);
      float4 q1 = ld4(ea, ef, (size_t)e * 4 + 1);
      float4 q2 = ld4(ea, ef, (size_t)e * 4 + 2);
      float4 q3 = ld4(ea, ef, (size_t)e * 4 + 3);
      float av[16] = {q0.x, q0.y, q0.z, q0.w, q1.x, q1.y, q1.z, q1.w,
                      q2.x, q2.y, q2.z, q2.w, q3.x, q3.y, q3.z, q3.w};
      float z0 = 0.f, z1 = 0.f;
#pragma unroll
      for (int k = 0; k < EDGE_DIM; ++k) {
        z0 += av[k] * wex[k];
        z1 += av[k] * wey[k];
      }
      acc0 += fmaxf(bf2f((ushort)(yu & 0xFFFF)) + z0, 0.f);
      acc1 += fmaxf(bf2f((ushort)(yu >> 16)) + z1, 0.f);
    }
    agg[(size_t)n * CH + c0] = acc0;
    agg[(size_t)n * CH + c1] = acc1;
  }
}

__global__ __launch_bounds__(256) void agg_csr(const uint* __restrict__ ybf,
                                               const uint* __restrict__ eabf,
                                               const void* __restrict__ ea,
                                               const ushort* __restrict__ wze,
                                               const void* __restrict__ W,
                                               const int* __restrict__ rowptr,
                                               const int2* __restrict__ sev,
                                               const int* __restrict__ flags,
                                               ushort* __restrict__ aggbf,
                                               float* __restrict__ aggf) {
  const int wave = threadIdx.x >> 6;
  const int lane = threadIdx.x & 63;
  const int n0 = (blockIdx.x * 4 + wave) * 8;  // grid = N/32 exactly
  const int ef = flags[2], wf = flags[3], MAP = flags[4];
  if (MAP == 0)      agg_mfma_body<0>(ybf, eabf, wze, rowptr, sev, aggbf, n0, lane);
  else if (MAP == 1) agg_mfma_body<1>(ybf, eabf, wze, rowptr, sev, aggbf, n0, lane);
  else               agg_f32_body(ybf, ea, ef, W, wf, rowptr, sev, aggf, n0, lane);
}

// ---------------------------------------------------------------- update GEMM on MFMA + fused norm
// agg half staged directly from aggbf (bf16 mean, no cvt, no rowptr). Output:
// bf16 to outbf (layer-1 h) or f32 to outf (layer-2 final).
template <int MAP>
__device__ __forceinline__ void upd_mfma_body(const void* __restrict__ x, int xf,
                                              const ushort* __restrict__ aggbf,
                                              const ushort* __restrict__ wsh,
                                              const void* __restrict__ bupd, int wf,
                                              const void* __restrict__ bias,
                                              float* __restrict__ outf,
                                              ushort* __restrict__ outbf, int relu,
                                              int n0, int lane, char* lds) {
  const int srow = lane >> 2;
  const int q = lane & 3;
  {
    uint sw = (uint)((srow & 7) << 4);
#pragma unroll
    for (int i = 0; i < 8; ++i) {
      int qi = q + 4 * i;
      uint2 pk;
      if (xf) {
        float4 v = ((const float4*)x)[(size_t)(n0 + srow) * 32 + qi];
        pk.x = (uint)f2bf(v.x) | ((uint)f2bf(v.y) << 16);
        pk.y = (uint)f2bf(v.z) | ((uint)f2bf(v.w) << 16);
      } else {
        pk = ((const uint2*)x)[(size_t)(n0 + srow) * 32 + qi];
      }
      *(uint2*)(lds + (((uint)srow * 512u + (uint)qi * 8u) ^ sw)) = pk;
      uint2 pa = ((const uint2*)aggbf)[(size_t)(n0 + srow) * 32 + qi];
      *(uint2*)(lds + (((uint)srow * 512u + 256u + (uint)qi * 8u) ^ sw)) = pa;
    }
  }
  asm volatile("s_waitcnt lgkmcnt(0) vmcnt(0)" ::: "memory");
  __builtin_amdgcn_sched_barrier(0);

  const int col = lane & 15, g = lane >> 4;
  const int ra = lane & 15;
  const uint asw = (uint)((ra & 7) << 4);
  f32x4 acc[8];
#pragma unroll
  for (int t = 0; t < 8; ++t) acc[t] = (f32x4){0.f, 0.f, 0.f, 0.f};

#pragma unroll
  for (int step = 0; step < 8; ++step) {
    short8v a;
    if (MAP) {
      uint byte = (uint)ra * 512u + (uint)(step * 32 + 8 * g) * 2u;
      *(uint4*)&a = *(const uint4*)(lds + (byte ^ asw));
    } else {
      uint b0 = (uint)ra * 512u + (uint)(step * 32 + 4 * g) * 2u;
      uint b1 = b0 + 32u;
      uint2 lo = *(const uint2*)(lds + (b0 ^ asw));
      uint2 hi = *(const uint2*)(lds + (b1 ^ asw));
      uint4 pk = make_uint4(lo.x, lo.y, hi.x, hi.y);
      *(uint4*)&a = pk;
    }
#pragma unroll
    for (int t = 0; t < 8; ++t) {
      short8v b = *(const short8v*)(wsh + ((size_t)(t * 8 + step) * 512 + lane * 8));
      acc[t] = __builtin_amdgcn_mfma_f32_16x16x32_bf16(a, b, acc[t], 0, 0, 0);
    }
  }

  float bu[8], bi[8];
#pragma unroll
  for (int t = 0; t < 8; ++t) {
    bu[t] = ldf(bupd, wf, t * 16 + col);
    bi[t] = ldf(bias, wf, t * 16 + col);
  }
  float raw[8][4];
  float ss[4] = {0.f, 0.f, 0.f, 0.f};
#pragma unroll
  for (int t = 0; t < 8; ++t)
#pragma unroll
    for (int r = 0; r < 4; ++r) {
      float v = acc[t][r] + bu[t];
      raw[t][r] = v;
      ss[r] += v * v;
    }
#pragma unroll
  for (int r = 0; r < 4; ++r)
#pragma unroll
    for (int o = 1; o < 16; o <<= 1) ss[r] += __shfl_xor(ss[r], o);
#pragma unroll
  for (int r = 0; r < 4; ++r) {
    float inv = 1.0f / fmaxf(sqrtf(ss[r]), 1e-12f);
    int row = g * 4 + r;
#pragma unroll
    for (int t = 0; t < 8; ++t) {
      float o = raw[t][r] * inv + bi[t];
      if (relu) o = fmaxf(o, 0.f);
      if (outbf) outbf[(size_t)(n0 + row) * CH + t * 16 + col] = f2bf(o);
      else       outf[(size_t)(n0 + row) * CH + t * 16 + col] = o;
    }
  }
}

// f32 fallback: reads f32 agg + rowptr (inv here), writes f32 out.
__device__ __forceinline__ void upd_f32_body(const void* __restrict__ x, int xf,
                                             const float* __restrict__ agg,
                                             const int* __restrict__ rowptr,
                                             const void* __restrict__ W, int wf,
                                             const void* __restrict__ bupd,
                                             const void* __restrict__ bias,
                                             float* __restrict__ out, int relu,
                                             int wave_n0, int lane, char* ldsc) {
  float* xs = (float*)ldsc;  // [8][256] f32 = 8 KB per-wave slice
  for (int c = 0; c < 2; ++c) {
    int n0 = wave_n0 + c * 8;
#pragma unroll
    for (int r = 0; r < NPW; ++r) {
      int n = n0 + r;
      float2 a = ld2(x, xf, (size_t)n * 64 + lane);
      xs[r * 256 + 2 * lane]     = a.x;
      xs[r * 256 + 2 * lane + 1] = a.y;
      int cd = rowptr[n + 1] - rowptr[n];
      float inv = 1.f / (float)(cd > 1 ? cd : 1);
      xs[r * 256 + CH + 2 * lane]     = agg[(size_t)n * CH + 2 * lane] * inv;
      xs[r * 256 + CH + 2 * lane + 1] = agg[(size_t)n * CH + 2 * lane + 1] * inv;
    }
    asm volatile("s_waitcnt lgkmcnt(0)" ::: "memory");
    __builtin_amdgcn_sched_barrier(0);

    float acc0[NPW], acc1[NPW];
#pragma unroll
    for (int r = 0; r < NPW; ++r) { acc0[r] = 0.f; acc1[r] = 0.f; }
#pragma unroll 4
    for (int k = 0; k < KUPD; k += 2) {
      float2 w0 = ld2(W, wf, (size_t)k * 64 + lane);
      float2 w1 = ld2(W, wf, (size_t)(k + 1) * 64 + lane);
#pragma unroll
      for (int r = 0; r < NPW; ++r) {
        float2 a = *(const float2*)&xs[r * 256 + k];
        acc0[r] += a.x * w0.x;
        acc1[r] += a.x * w0.y;
        acc0[r] += a.y * w1.x;
        acc1[r] += a.y * w1.y;
      }
    }
    float2 b  = ld2(bupd, wf, lane);
    float2 bi = ld2(bias, wf, lane);
#pragma unroll
    for (int r = 0; r < NPW; ++r) {
      float r0 = acc0[r] + b.x;
      float r1 = acc1[r] + b.y;
      float sq = r0 * r0 + r1 * r1;
#pragma unroll
      for (int o = 32; o; o >>= 1) sq += __shfl_xor(sq, o);
      float innv = 1.0f / fmaxf(sqrtf(sq), 1e-12f);
      float o0 = r0 * innv + bi.x;
      float o1 = r1 * innv + bi.y;
      if (relu) { o0 = fmaxf(o0, 0.f); o1 = fmaxf(o1, 0.f); }
      size_t n = (size_t)(n0 + r);
      out[n * CH + 2 * lane]     = o0;
      out[n * CH + 2 * lane + 1] = o1;
    }
  }
}

// xa/sa: MFMA-path input; xb/sb: fallback input. outbf != null -> bf16 output
// (layer-1 h); fallback always writes f32 outf.
__global__ __launch_bounds__(256) void upd_fused(const void* __restrict__ xa, int sa,
                                                 const void* __restrict__ xb, int sb,
                                                 const ushort* __restrict__ aggbf,
                                                 const float* __restrict__ aggf,
                                                 const int* __restrict__ rowptr,
                                                 const ushort* __restrict__ wsh,
                                                 const void* __restrict__ W,
                                                 const void* __restrict__ bupd,
                                                 const void* __restrict__ bias,
                                                 const int* __restrict__ flags,
                                                 float* __restrict__ outf,
                                                 ushort* __restrict__ outbf,
                                                 int relu) {
  __shared__ char lds[32768];  // 8 KB per wave
  const int wave = threadIdx.x >> 6;
  const int lane = threadIdx.x & 63;
  const int wid = blockIdx.x * 4 + wave;
  if (wid >= N_NODES / 16) return;
  const int n0 = wid * 16;
  const int wf = flags[3];
  const int MAP = flags[4];
  char* myl = lds + wave * 8192;
  if (MAP == 0)
    upd_mfma_body<0>(xa, resolve_f32(sa, flags), aggbf, wsh, bupd, wf, bias, outf, outbf, relu, n0, lane, myl);
  else if (MAP == 1)
    upd_mfma_body<1>(xa, resolve_f32(sa, flags), aggbf, wsh, bupd, wf, bias, outf, outbf, relu, n0, lane, myl);
  else
    upd_f32_body(xb, resolve_f32(sb, flags), aggf, rowptr, W, wf, bupd, bias, outf, relu, n0, lane, myl);
}

// ---------------------------------------------------------------- host
extern "C" void kernel_launch(void* const* d_in, const int* in_sizes, int n_in,
                              void* d_out, int out_size, void* d_ws, size_t ws_size,
                              hipStream_t stream) {
  const void* x   = d_in[0];
  const int*  ei  = (const int*)d_in[1];
  const void* ea  = d_in[2];
  const void* wm1 = d_in[3];
  const void* bm1 = d_in[4];
  const void* wu1 = d_in[5];
  const void* bu1 = d_in[6];
  const void* bi1 = d_in[7];
  const void* wm2 = d_in[8];
  const void* bm2 = d_in[9];
  const void* wu2 = d_in[10];
  const void* bu2 = d_in[11];
  const void* bi2 = d_in[12];
  float* out = (float*)d_out;

  char* base = (char*)d_ws;
  size_t off = 0;
  auto alloc = [&](size_t b) { size_t o = off; off += (b + 255) & ~(size_t)255; return o; };
  size_t flags_o = alloc(32);
  size_t cnt_o   = alloc((size_t)N_NODES * 4);
  size_t fill_o  = alloc((size_t)N_NODES * 4);
  size_t zero_end = off;                       // memset covers flags|cnt|fill only
  size_t rowp_o  = alloc((size_t)(N_NODES + 1) * 4);
  size_t sev_o   = alloc((size_t)N_EDGES * 8);
  size_t agg_o   = alloc((size_t)N_NODES * CH * 4);        // f32 fallback; bf16 mean aliases
  size_t y_o     = alloc((size_t)(N_NODES + 1) * CH * 2);  // packed bf16 + zero row
  size_t hbf_o   = alloc((size_t)N_NODES * CH * 2);        // layer-1 h as bf16
  size_t eabf_o  = alloc((size_t)N_EDGES * EDGE_DIM * 2);  // edge attrs bf16, 51MB
  size_t wsh1_o  = alloc((size_t)4096 * 8 * 2);
  size_t wsh2_o  = alloc((size_t)4096 * 8 * 2);
  size_t wshm1_o = alloc((size_t)2048 * 8 * 2);
  size_t wshm2_o = alloc((size_t)2048 * 8 * 2);
  size_t wze1_o  = alloc((size_t)512 * 8 * 2);
  size_t wze2_o  = alloc((size_t)512 * 8 * 2);
  (void)ws_size; (void)n_in; (void)in_sizes; (void)out_size;

  int*    flags = (int*)(base + flags_o);
  int*    cntp  = (int*)(base + cnt_o);
  int*    fillp = (int*)(base + fill_o);
  int*    rowp  = (int*)(base + rowp_o);
  int2*   sevp  = (int2*)(base + sev_o);
  float*  aggf  = (float*)(base + agg_o);
  ushort* aggbf = (ushort*)(base + agg_o);   // alias (MAP-uniform selection)
  uint*   ybfp  = (uint*)(base + y_o);
  ushort* hbfp  = (ushort*)(base + hbf_o);
  uint*   eabfp = (uint*)(base + eabf_o);
  ushort* wsh1  = (ushort*)(base + wsh1_o);
  ushort* wsh2  = (ushort*)(base + wsh2_o);
  ushort* wshm1 = (ushort*)(base + wshm1_o);
  ushort* wshm2 = (ushort*)(base + wshm2_o);
  ushort* wze1  = (ushort*)(base + wze1_o);
  ushort* wze2  = (ushort*)(base + wze2_o);
  float*  hp    = out;  // fallback-path layer-1 h (f32) lives in d_out

  hipMemsetAsync(base, 0, zero_end, stream);
  detect_probe<<<1, 256, 0, stream>>>(ei, (const ushort*)x, (const ushort*)ea,
                                      (const ushort*)wm1, flags);
  count_kernel<<<(N_EDGES + 255) / 256, 256, 0, stream>>>(ei, flags, cntp);
  scan_kernel<<<1, 1024, 0, stream>>>(cntp, rowp);
  scatter_kernel<<<(N_EDGES + 255) / 256, 256, 0, stream>>>(ei, ea, flags, rowp,
                                                            fillp, sevp, eabfp);
  wshuf_all<<<53, 256, 0, stream>>>(wu1, wu2, wm1, wm2, flags,
                                    wsh1, wsh2, wshm1, wshm2, wze1, wze2, ybfp);

  const int agrid = N_NODES / 32;            // 3125 (4 waves x 8 nodes)
  const int wgrid = (N_NODES / 16 + 3) / 4;  // 1563 (4 waves x 16 rows)

  // ---- layer 1
  gemm_node<<<wgrid, 256, 0, stream>>>(x, 1, x, 1, wshm1, wm1, bm1, flags, ybfp);
  agg_csr<<<agrid, 256, 0, stream>>>(ybfp, eabfp, ea, wze1, wm1, rowp, sevp, flags,
                                     aggbf, aggf);
  upd_fused<<<wgrid, 256, 0, stream>>>(x, 1, x, 1, aggbf, aggf, rowp, wsh1, wu1,
                                       bu1, bi1, flags, hp, hbfp, 1);

  // ---- layer 2 (MFMA path reads hbf bf16; fallback reads h f32 in d_out)
  gemm_node<<<wgrid, 256, 0, stream>>>(hbfp, 0, hp, 2, wshm2, wm2, bm2, flags, ybfp);
  agg_csr<<<agrid, 256, 0, stream>>>(ybfp, eabfp, ea, wze2, wm2, rowp, sevp, flags,
                                     aggbf, aggf);
  upd_fused<<<wgrid, 256, 0, stream>>>(hbfp, 0, hp, 2, aggbf, aggf, rowp, wsh2, wu2,
                                       bu2, bi2, flags, out, (ushort*)nullptr, 0);
}